// Round 2
// baseline (578.045 us; speedup 1.0000x reference)
//
#include <hip/hip_runtime.h>
#include <hip/hip_bf16.h>

typedef __hip_bfloat16 bf16;
typedef __attribute__((ext_vector_type(8))) short short8;
typedef __attribute__((ext_vector_type(4))) float f32x4;
typedef __attribute__((ext_vector_type(8))) __bf16 bf16x8;

#define NB 32768
#define DD 768
#define AA 17
#define HH 128

__device__ __forceinline__ float bs2f(short s){
  unsigned int u = ((unsigned int)(unsigned short)s) << 16;
  return __builtin_bit_cast(float, u);
}
__device__ __forceinline__ short f2bs(float f){
  bf16 h = __float2bfloat16(f);
  return __builtin_bit_cast(short, h);
}
__device__ __forceinline__ f32x4 mfma16(short8 a, short8 b, f32x4 c){
  return __builtin_amdgcn_mfma_f32_16x16x32_bf16(
      __builtin_bit_cast(bf16x8, a), __builtin_bit_cast(bf16x8, b), c, 0, 0, 0);
}

// load 8 consecutive elements starting at elem_off; convert to bf16 if F32
template<int F32>
__device__ __forceinline__ short8 ldchunk(const void* base, long elem_off){
  if (F32){
    const float4* p = (const float4*)((const float*)base + elem_off);
    float4 x = p[0], y = p[1];
    short8 r;
    r[0]=f2bs(x.x); r[1]=f2bs(x.y); r[2]=f2bs(x.z); r[3]=f2bs(x.w);
    r[4]=f2bs(y.x); r[5]=f2bs(y.y); r[6]=f2bs(y.z); r[7]=f2bs(y.w);
    return r;
  } else {
    return *(const short8*)((const short*)base + elem_off);
  }
}

// ---------------- prep kernels (all inputs fp32) ----------------

__device__ __forceinline__ float blk_mean128(float v, float* tmp){
  int t = threadIdx.x;
  #pragma unroll
  for (int m = 32; m; m >>= 1) v += __shfl_xor(v, m);
  if ((t & 63) == 0) tmp[t >> 6] = v;
  __syncthreads();
  float r = (tmp[0] + tmp[1]) * (1.0f / 128.0f);
  __syncthreads();
  return r;
}

__global__ void prep1(const float* __restrict__ w_tok, const float* __restrict__ b_tok,
                      const float* __restrict__ pos, const float* __restrict__ g_auln,
                      float* __restrict__ ug, float* __restrict__ rg, float* __restrict__ coef){
  __shared__ float tmp[2];
  int h = threadIdx.x;
  float w = w_tok[h];
  float wbar = blk_mean128(w, tmp);
  float u = w - wbar;
  float g = g_auln[h];
  ug[h] = u * g;
  float muu = blk_mean128(u * u, tmp);
  if (h == 0) coef[0] = muu;
  float bt = b_tok[h];
  for (int a = 0; a < AA; ++a){
    float c = bt + pos[a * HH + h];
    float cbar = blk_mean128(c, tmp);
    float r = c - cbar;
    rg[a * HH + h] = r * g;
    float mur = blk_mean128(u * r, tmp);
    float mrr = blk_mean128(r * r, tmp);
    if (h == 0){ coef[1 + a] = mur; coef[18 + a] = mrr; }
  }
}

__global__ void prep2(const float* __restrict__ w_in, const float* __restrict__ b_in,
                      const float* __restrict__ b_auln, const float* __restrict__ b_q,
                      const float* __restrict__ ug, const float* __restrict__ rg,
                      float* __restrict__ Uk, float* __restrict__ Ck,
                      float* __restrict__ Uv, float* __restrict__ Cv,
                      float* __restrict__ Rk, float* __restrict__ Rv,
                      float* __restrict__ bqf){
  int hp = threadIdx.x, bid = blockIdx.x;
  const float* wqrow = w_in + (long)hp * HH;
  const float* wkrow = w_in + (long)(HH + hp) * HH;
  const float* wvrow = w_in + (long)(2 * HH + hp) * HH;
  if (bid < AA){
    int a = bid;
    float sk = 0.f, sv = 0.f;
    for (int t = 0; t < HH; ++t){
      float r = rg[a * HH + t];
      sk += r * wkrow[t];
      sv += r * wvrow[t];
    }
    Rk[a * HH + hp] = sk; Rv[a * HH + hp] = sv;
  } else if (bid == AA){
    float uk = 0.f, uv = 0.f, ck = 0.f, cv = 0.f;
    for (int t = 0; t < HH; ++t){
      float u = ug[t], ba = b_auln[t];
      float wk = wkrow[t], wv = wvrow[t];
      uk += u * wk; uv += u * wv; ck += ba * wk; cv += ba * wv;
    }
    Uk[hp] = uk; Uv[hp] = uv;
    Ck[hp] = ck + b_in[HH + hp];
    Cv[hp] = cv + b_in[2 * HH + hp];
  } else {
    float s = 0.f;
    for (int t = 0; t < HH; ++t) s += b_q[t] * wqrow[t];
    bqf[hp] = s + b_in[hp];
  }
}

// Wqf[h][j] = sum_t w_in[h][t] * w_q[t][j]  (bf16 out, internal)
__global__ void prep_wqf(const float* __restrict__ w_in, const float* __restrict__ w_q,
                         bf16* __restrict__ Wqf){
  __shared__ float wq[HH];
  int h = blockIdx.x, t = threadIdx.x;
  if (t < HH) wq[t] = w_in[(long)h * HH + t];
  __syncthreads();
  for (int j = t; j < DD; j += 256){
    float acc = 0.f;
    for (int k = 0; k < HH; ++k) acc += wq[k] * w_q[(long)k * DD + j];
    Wqf[(long)h * DD + j] = __float2bfloat16(acc);
  }
}

// Gate-path precompute (one block per output column c of D):
//   Wg1b[c][j]  = bf16(w_gate[c][j])                      j<768   (phase-1 B)
//   Wg2w[c][t]  = bf16( sum_j w_gate[c][768+j]*w_out[j][t] )      (folded phase-2 B)
//   Woutb[c][t] = bf16(w_out[c][t])                               (af B)
//   bgp[c]      = b_gate[c] + sum_j w_gate[c][768+j]*b_out[j]
__global__ void prep_gate(const float* __restrict__ w_gate, const float* __restrict__ b_gate,
                          const float* __restrict__ w_out, const float* __restrict__ b_out,
                          bf16* __restrict__ Wg1b, bf16* __restrict__ Wg2w,
                          bf16* __restrict__ Woutb, float* __restrict__ bgp){
  __shared__ float wg2[DD];
  __shared__ float red[2];
  int c = blockIdx.x, t = threadIdx.x;
  const float* wrow = w_gate + (long)c * (2 * DD);
  for (int j = t; j < DD; j += 128){
    Wg1b[(long)c * DD + j] = __float2bfloat16(wrow[j]);
    wg2[j] = wrow[DD + j];
  }
  __syncthreads();
  float acc = 0.f;
  for (int j = 0; j < DD; ++j) acc = fmaf(wg2[j], w_out[(long)j * HH + t], acc);
  Wg2w[(long)c * HH + t] = __float2bfloat16(acc);
  Woutb[(long)c * HH + t] = __float2bfloat16(w_out[(long)c * HH + t]);
  float pb = 0.f;
  for (int j = t; j < DD; j += 128) pb = fmaf(wg2[j], b_out[j], pb);
  #pragma unroll
  for (int m = 32; m; m >>= 1) pb += __shfl_xor(pb, m);
  if ((t & 63) == 0) red[t >> 6] = pb;
  __syncthreads();
  if (t == 0) bgp[c] = b_gate[c] + red[0] + red[1];
}

// ---------------- attention (folded K/V) ----------------
__global__ __launch_bounds__(128) void attn(
    const bf16* __restrict__ Q, const float* __restrict__ au, const float* __restrict__ coef,
    const float* __restrict__ Uk_, const float* __restrict__ Ck_,
    const float* __restrict__ Uv_, const float* __restrict__ Cv_,
    const float* __restrict__ Rk, const float* __restrict__ Rv,
    bf16* __restrict__ ctx){
  const int ROWS = 8;
  int h = threadIdx.x;
  long row0 = (long)blockIdx.x * ROWS;
  float Uk = Uk_[h], Ck = Ck_[h], Uv = Uv_[h], Cv = Cv_[h];
  float cA = coef[0];
  __shared__ float sa[ROWS * AA];
  for (int idx = h; idx < ROWS * AA; idx += 128)
    sa[idx] = au[row0 * AA + idx];
  __syncthreads();
  const float scale = 0.17677669529663689f; // 1/sqrt(32)
  for (int r = 0; r < ROWS; ++r){
    long row = row0 + r;
    float q = __bfloat162float(Q[row * HH + h]);
    float sc[AA], vv[AA];
    #pragma unroll
    for (int a = 0; a < AA; ++a){
      float s = sa[r * AA + a];
      float var = fmaf(s * s, cA, fmaf(2.f * s, coef[1 + a], coef[18 + a]));
      float rinv = rsqrtf(fmaxf(var, 0.f) + 1e-5f);
      float kk = fmaf(s, Uk, Rk[a * HH + h]) * rinv + Ck;
      vv[a]    = fmaf(s, Uv, Rv[a * HH + h]) * rinv + Cv;
      float p = q * kk;
      p += __shfl_xor(p, 16); p += __shfl_xor(p, 8); p += __shfl_xor(p, 4);
      p += __shfl_xor(p, 2);  p += __shfl_xor(p, 1);
      sc[a] = p * scale;
    }
    float mx = sc[0];
    #pragma unroll
    for (int a = 1; a < AA; ++a) mx = fmaxf(mx, sc[a]);
    float den = 0.f, cval = 0.f;
    #pragma unroll
    for (int a = 0; a < AA; ++a){
      float e = __expf(sc[a] - mx);
      den += e; cval += e * vv[a];
    }
    ctx[row * HH + h] = __float2bfloat16(cval / den);
  }
}

// ---------------- MFMA GEMM (A row-major MxK, B row-major NxK i.e. B^T) ----------------
// Double-buffered LDS, ONE barrier per K-step:
//   bar -> issue loads(kt+1) -> ds_read frags(kt) -> MFMA(kt) -> ds_write buf^1(kt+1)
// MODE 0: out = acc + bias                 -> bf16 (internal)
// MODE 1: out = LayerNorm(acc + bias)*g+b  -> bf16 (internal, full 128-col tile)
// SIDE 1: also write the bf16-converted A tile to sideA (same element pitch as lda)
template<int MODE, int AF, int BF, int SIDE>
__global__ __launch_bounds__(256) void gemm_bt(
    const void* __restrict__ A, long lda, int ks,
    const void* __restrict__ Bw, long ldb,
    const float* __restrict__ bias,
    const float* __restrict__ g_ln, const float* __restrict__ b_ln,
    short* __restrict__ sideA,
    bf16* __restrict__ C, long ldc)
{
  // buf k: As at k*10240, Bs at k*10240+5120 (each 128x40 shorts). epilogue reuses [0,17408)
  __shared__ __align__(16) short smem[20480];
  const int tid = threadIdx.x;
  const int w = tid >> 6, l = tid & 63;
  const long rowBase = (long)blockIdx.y * 128;
  const int colBase = blockIdx.x * 128;
  const int fr = l & 15;          // frag: C/D col within 16 / A row within 16
  const int kq = l >> 4;          // frag k-quad
  const int sr0 = tid >> 2,         sp0 = (tid & 3) * 8;
  const int sr1 = (tid + 256) >> 2;

  f32x4 acc[2][8];
  f32x4 zero = {0.f, 0.f, 0.f, 0.f};
  #pragma unroll
  for (int i = 0; i < 2; ++i)
    #pragma unroll
    for (int j = 0; j < 8; ++j) acc[i][j] = zero;

  // prologue: stage kt=0 into buf0
  {
    short8 av0 = ldchunk<AF>(A, (rowBase + sr0) * lda + sp0);
    short8 av1 = ldchunk<AF>(A, (rowBase + sr1) * lda + sp0);
    short8 bv0 = ldchunk<BF>(Bw, (long)(colBase + sr0) * ldb + sp0);
    short8 bv1 = ldchunk<BF>(Bw, (long)(colBase + sr1) * ldb + sp0);
    if (SIDE){
      *(short8*)(sideA + (rowBase + sr0) * lda + sp0) = av0;
      *(short8*)(sideA + (rowBase + sr1) * lda + sp0) = av1;
    }
    *(short8*)(smem + sr0 * 40 + sp0) = av0;
    *(short8*)(smem + sr1 * 40 + sp0) = av1;
    *(short8*)(smem + 5120 + sr0 * 40 + sp0) = bv0;
    *(short8*)(smem + 5120 + sr1 * 40 + sp0) = bv1;
  }

  for (int kt = 0; kt < ks; ++kt){
    __syncthreads();   // buf[kt&1] staged & prior reads of buf[(kt+1)&1] done
    short* cb = smem + (kt & 1) * 10240;
    short* nb = smem + ((kt + 1) & 1) * 10240;
    const bool pf = (kt + 1 < ks);
    short8 av0, av1, bv0, bv1;
    if (pf){
      const long kA = (long)(kt + 1) * 32;
      av0 = ldchunk<AF>(A, (rowBase + sr0) * lda + kA + sp0);
      av1 = ldchunk<AF>(A, (rowBase + sr1) * lda + kA + sp0);
      bv0 = ldchunk<BF>(Bw, (long)(colBase + sr0) * ldb + kA + sp0);
      bv1 = ldchunk<BF>(Bw, (long)(colBase + sr1) * ldb + kA + sp0);
      if (SIDE){
        *(short8*)(sideA + (rowBase + sr0) * lda + kA + sp0) = av0;
        *(short8*)(sideA + (rowBase + sr1) * lda + kA + sp0) = av1;
      }
    }
    const int ra0 = w * 32 + fr;
    short8 a0 = *(const short8*)(cb + ra0 * 40 + kq * 8);
    short8 a1 = *(const short8*)(cb + (ra0 + 16) * 40 + kq * 8);
    #pragma unroll
    for (int nt = 0; nt < 8; ++nt){
      short8 b = *(const short8*)(cb + 5120 + (nt * 16 + fr) * 40 + kq * 8);
      acc[0][nt] = mfma16(a0, b, acc[0][nt]);
      acc[1][nt] = mfma16(a1, b, acc[1][nt]);
    }
    if (pf){
      *(short8*)(nb + sr0 * 40 + sp0) = av0;
      *(short8*)(nb + sr1 * 40 + sp0) = av1;
      *(short8*)(nb + 5120 + sr0 * 40 + sp0) = bv0;
      *(short8*)(nb + 5120 + sr1 * 40 + sp0) = bv1;
    }
  }
  __syncthreads();  // last frag reads done before epilogue overwrites LDS

  // ---- epilogue: frags -> LDS (bf16) ----
  short* ep = smem;
  if (MODE == 1){
    #pragma unroll
    for (int mt = 0; mt < 2; ++mt){
      #pragma unroll
      for (int r = 0; r < 4; ++r){
        float x[8]; float sm = 0.f, sq = 0.f;
        #pragma unroll
        for (int nt = 0; nt < 8; ++nt){
          const int col = colBase + nt * 16 + fr;
          x[nt] = acc[mt][nt][r] + bias[col];
          sm += x[nt]; sq += x[nt] * x[nt];
        }
        sm += __shfl_xor(sm, 1); sq += __shfl_xor(sq, 1);
        sm += __shfl_xor(sm, 2); sq += __shfl_xor(sq, 2);
        sm += __shfl_xor(sm, 4); sq += __shfl_xor(sq, 4);
        sm += __shfl_xor(sm, 8); sq += __shfl_xor(sq, 8);
        const float mu = sm * (1.f / 128.f);
        const float var = sq * (1.f / 128.f) - mu * mu;
        const float rinv = rsqrtf(fmaxf(var, 0.f) + 1e-5f);
        const int lrow = w * 32 + mt * 16 + kq * 4 + r;
        #pragma unroll
        for (int nt = 0; nt < 8; ++nt){
          const int col = colBase + nt * 16 + fr;
          float y = (x[nt] - mu) * rinv * g_ln[col] + b_ln[col];
          ep[lrow * 136 + nt * 16 + fr] = f2bs(y);
        }
      }
    }
  } else {
    #pragma unroll
    for (int nt = 0; nt < 8; ++nt){
      const int col = colBase + nt * 16 + fr;
      const float bv = bias[col];
      #pragma unroll
      for (int mt = 0; mt < 2; ++mt){
        const int lrow0 = w * 32 + mt * 16 + kq * 4;
        #pragma unroll
        for (int r = 0; r < 4; ++r)
          ep[(lrow0 + r) * 136 + nt * 16 + fr] = f2bs(acc[mt][nt][r] + bv);
      }
    }
  }
  __syncthreads();

  // ---- coalesced bf16 store pass ----
  #pragma unroll
  for (int it = 0; it < 8; ++it){
    const int cid = tid + it * 256;
    const int rw = cid >> 4;
    const int cc = (cid & 15) * 8;
    const long gr = rowBase + rw;
    short8 vls = *(const short8*)(ep + rw * 136 + cc);
    short* cp = (short*)C + gr * ldc + colBase + cc;
    *(short8*)cp = vls;
  }
}

// ---------------- fused gate GEMM ----------------
// accG = A1(visual) @ Wg1b^T  (K=768)  +  aon @ Wg2w^T (K=128)  [gate logits]
// accF = aon @ Woutb^T        (K=128)                           [attn_feat tile]
// out  = sigmoid(accG+bgp) * (accF+b_out) + (1-gate) * visual_fp32
// Phase 1: double-buffered, one barrier per K-step. Phase 2: 4 steps, classic.
template<int A1F>
__global__ __launch_bounds__(256) void gemm_final(
    const void* __restrict__ A1,           // visual: bf16 (A1F=0) or fp32 (A1F=1), pitch DD
    const bf16* __restrict__ aon,          // NB x HH
    const bf16* __restrict__ Wg1b,         // DD x DD
    const bf16* __restrict__ Wg2w,         // DD x HH
    const bf16* __restrict__ Woutb,        // DD x HH
    const float* __restrict__ bgp,         // DD (folded gate bias)
    const float* __restrict__ b_out,       // DD
    const float* __restrict__ vf,          // visual fp32 (epilogue mix)
    float* __restrict__ C)                 // NB x DD fp32
{
  __shared__ __align__(16) short smem[20480]; // 2 x (As+Bs); phase2 uses 3 x 5120-tiles
  const int tid = threadIdx.x;
  const int w = tid >> 6, l = tid & 63;

  // bijective XCD swizzle: nwg = 6*256 = 1536, divisible by 8.
  const int nx = 6;
  const int bid = blockIdx.y * nx + blockIdx.x;   // hw dispatch order (x fastest)
  const int cpx = (NB / 128) * nx / 8;            // 192 blocks per XCD chunk
  const int swz = (bid & 7) * cpx + (bid >> 3);
  const long rowBase = (long)(swz / nx) * 128;
  const int colBase = (swz % nx) * 128;

  const int fr = l & 15;
  const int kq = l >> 4;
  const int sr0 = tid >> 2,         sp0 = (tid & 3) * 8;
  const int sr1 = (tid + 256) >> 2;

  f32x4 accG[2][8], accF[2][8];
  f32x4 zero = {0.f, 0.f, 0.f, 0.f};
  #pragma unroll
  for (int i = 0; i < 2; ++i)
    #pragma unroll
    for (int j = 0; j < 8; ++j){ accG[i][j] = zero; accF[i][j] = zero; }

  // ---- phase 1: visual @ Wg1b^T, K = 768, double-buffered ----
  {
    short8 av0 = ldchunk<A1F>(A1, (rowBase + sr0) * DD + sp0);
    short8 av1 = ldchunk<A1F>(A1, (rowBase + sr1) * DD + sp0);
    short8 bv0 = *(const short8*)((const short*)Wg1b + (long)(colBase + sr0) * DD + sp0);
    short8 bv1 = *(const short8*)((const short*)Wg1b + (long)(colBase + sr1) * DD + sp0);
    *(short8*)(smem + sr0 * 40 + sp0) = av0;
    *(short8*)(smem + sr1 * 40 + sp0) = av1;
    *(short8*)(smem + 5120 + sr0 * 40 + sp0) = bv0;
    *(short8*)(smem + 5120 + sr1 * 40 + sp0) = bv1;
  }
  for (int kt = 0; kt < DD / 32; ++kt){
    __syncthreads();
    short* cb = smem + (kt & 1) * 10240;
    short* nb = smem + ((kt + 1) & 1) * 10240;
    const bool pf = (kt + 1 < DD / 32);
    short8 av0, av1, bv0, bv1;
    if (pf){
      const long kA = (long)(kt + 1) * 32;
      av0 = ldchunk<A1F>(A1, (rowBase + sr0) * DD + kA + sp0);
      av1 = ldchunk<A1F>(A1, (rowBase + sr1) * DD + kA + sp0);
      bv0 = *(const short8*)((const short*)Wg1b + (long)(colBase + sr0) * DD + kA + sp0);
      bv1 = *(const short8*)((const short*)Wg1b + (long)(colBase + sr1) * DD + kA + sp0);
    }
    const int ra0 = w * 32 + fr;
    short8 a0 = *(const short8*)(cb + ra0 * 40 + kq * 8);
    short8 a1 = *(const short8*)(cb + (ra0 + 16) * 40 + kq * 8);
    #pragma unroll
    for (int nt = 0; nt < 8; ++nt){
      short8 b = *(const short8*)(cb + 5120 + (nt * 16 + fr) * 40 + kq * 8);
      accG[0][nt] = mfma16(a0, b, accG[0][nt]);
      accG[1][nt] = mfma16(a1, b, accG[1][nt]);
    }
    if (pf){
      *(short8*)(nb + sr0 * 40 + sp0) = av0;
      *(short8*)(nb + sr1 * 40 + sp0) = av1;
      *(short8*)(nb + 5120 + sr0 * 40 + sp0) = bv0;
      *(short8*)(nb + 5120 + sr1 * 40 + sp0) = bv1;
    }
  }

  // ---- phase 2: aon @ {Wg2w, Woutb}^T, K = 128 (As=0, Bs=5120, Bs2=10240) ----
  short* As = smem;
  short* Bs = smem + 5120;
  short* Bs2 = smem + 10240;
  for (int kt = 0; kt < HH / 32; ++kt){
    const long kA = (long)kt * 32;
    short8 av0 = *(const short8*)((const short*)aon + (rowBase + sr0) * HH + kA + sp0);
    short8 av1 = *(const short8*)((const short*)aon + (rowBase + sr1) * HH + kA + sp0);
    short8 bv0 = *(const short8*)((const short*)Wg2w + (long)(colBase + sr0) * HH + kA + sp0);
    short8 bv1 = *(const short8*)((const short*)Wg2w + (long)(colBase + sr1) * HH + kA + sp0);
    short8 cv0 = *(const short8*)((const short*)Woutb + (long)(colBase + sr0) * HH + kA + sp0);
    short8 cv1 = *(const short8*)((const short*)Woutb + (long)(colBase + sr1) * HH + kA + sp0);
    __syncthreads();   // previous reads (phase1 tail / prior kt) complete
    *(short8*)(As + sr0 * 40 + sp0) = av0;
    *(short8*)(As + sr1 * 40 + sp0) = av1;
    *(short8*)(Bs + sr0 * 40 + sp0) = bv0;
    *(short8*)(Bs + sr1 * 40 + sp0) = bv1;
    *(short8*)(Bs2 + sr0 * 40 + sp0) = cv0;
    *(short8*)(Bs2 + sr1 * 40 + sp0) = cv1;
    __syncthreads();
    const int ra0 = w * 32 + fr;
    short8 a0 = *(const short8*)(As + ra0 * 40 + kq * 8);
    short8 a1 = *(const short8*)(As + (ra0 + 16) * 40 + kq * 8);
    #pragma unroll
    for (int nt = 0; nt < 8; ++nt){
      short8 b  = *(const short8*)(Bs  + (nt * 16 + fr) * 40 + kq * 8);
      short8 b2 = *(const short8*)(Bs2 + (nt * 16 + fr) * 40 + kq * 8);
      accG[0][nt] = mfma16(a0, b,  accG[0][nt]);
      accG[1][nt] = mfma16(a1, b,  accG[1][nt]);
      accF[0][nt] = mfma16(a0, b2, accF[0][nt]);
      accF[1][nt] = mfma16(a1, b2, accF[1][nt]);
    }
  }

  // ---- epilogue: gate-mix directly from registers (fp32 out) ----
  float bg[8], bo[8];
  #pragma unroll
  for (int nt = 0; nt < 8; ++nt){
    const int col = colBase + nt * 16 + fr;
    bg[nt] = bgp[col];
    bo[nt] = b_out[col];
  }
  #pragma unroll
  for (int mt = 0; mt < 2; ++mt){
    const long r0 = rowBase + w * 32 + mt * 16 + kq * 4;
    #pragma unroll
    for (int r = 0; r < 4; ++r){
      const long row = r0 + r;
      const float* vrow = vf + row * DD;
      float* crow = C + row * DD;
      #pragma unroll
      for (int nt = 0; nt < 8; ++nt){
        const int col = colBase + nt * 16 + fr;
        const float lin = accG[mt][nt][r] + bg[nt];
        const float afv = accF[mt][nt][r] + bo[nt];
        const float gate = 1.f / (1.f + __expf(-lin));
        crow[col] = gate * afv + (1.f - gate) * vrow[col];
      }
    }
  }
}

// ---------------- launch ----------------
// d_out carve (dead before gemm_final writes d_out): Q bf16 [0,8), ctx bf16 [8,16),
// tables [16,~16.3) MB. d_ws: aon + gate tables (~9.6 MB) + optional vbf 48 MB
// (engaged only if ws_size is large enough; all gemm_final INPUTS live outside d_out).
extern "C" void kernel_launch(void* const* d_in, const int* in_sizes, int n_in,
                              void* d_out, int out_size, void* d_ws, size_t ws_size,
                              hipStream_t stream){
  const float* visual = (const float*)d_in[0];
  const float* au     = (const float*)d_in[1];
  const float* w_tok  = (const float*)d_in[2];
  const float* b_tok  = (const float*)d_in[3];
  const float* pos    = (const float*)d_in[4];
  const float* g_auln = (const float*)d_in[5];
  const float* b_auln = (const float*)d_in[6];
  const float* w_q    = (const float*)d_in[7];
  const float* b_q    = (const float*)d_in[8];
  const float* w_in   = (const float*)d_in[9];
  const float* b_in   = (const float*)d_in[10];
  const float* w_ao   = (const float*)d_in[11];
  const float* b_ao   = (const float*)d_in[12];
  const float* g_aln  = (const float*)d_in[13];
  const float* b_aln  = (const float*)d_in[14];
  const float* w_out  = (const float*)d_in[15];
  const float* b_out  = (const float*)d_in[16];
  const float* w_gate = (const float*)d_in[17];
  const float* b_gate = (const float*)d_in[18];

  char* ob = (char*)d_out;
  bf16* Q   = (bf16*)(ob);                       // [0,8MB)
  bf16* ctx = (bf16*)(ob + ((size_t)8 << 20));   // [8,16MB)
  char* p = ob + ((size_t)16 << 20);             // tables (read only by pre-final kernels)
  auto alloc = [&](size_t bytes){ char* r = p; p += (bytes + 255) & ~(size_t)255; return r; };
  bf16*  Wqf  = (bf16*) alloc((size_t)HH * DD * 2);
  float* bqf  = (float*)alloc(HH * 4);
  float* ug   = (float*)alloc(HH * 4);
  float* rg   = (float*)alloc(AA * HH * 4);
  float* coef = (float*)alloc(64 * 4);
  float* Uk   = (float*)alloc(HH * 4);
  float* Ck   = (float*)alloc(HH * 4);
  float* Uv   = (float*)alloc(HH * 4);
  float* Cv   = (float*)alloc(HH * 4);
  float* Rk   = (float*)alloc(AA * HH * 4);
  float* Rv   = (float*)alloc(AA * HH * 4);

  // workspace carve: everything gemm_final READS must live here (it rewrites d_out)
  char* q = (char*)d_ws;
  auto walloc = [&](size_t bytes){ char* r = q; q += (bytes + 255) & ~(size_t)255; return r; };
  bf16*  aon   = (bf16*) walloc((size_t)NB * HH * 2);   // 8 MB
  bf16*  Wg1b  = (bf16*) walloc((size_t)DD * DD * 2);   // 1.125 MB
  bf16*  Wg2w  = (bf16*) walloc((size_t)DD * HH * 2);   // 192 KB
  bf16*  Woutb = (bf16*) walloc((size_t)DD * HH * 2);   // 192 KB
  float* bgp   = (float*)walloc(DD * 4);
  bf16*  vbf   = (bf16*) walloc((size_t)NB * DD * 2);   // 48 MB (optional)
  const bool use_vbf = (size_t)(q - (char*)d_ws) <= ws_size;

  prep1<<<dim3(1), dim3(128), 0, stream>>>(w_tok, b_tok, pos, g_auln, ug, rg, coef);
  prep2<<<dim3(19), dim3(128), 0, stream>>>(w_in, b_in, b_auln, b_q, ug, rg, Uk, Ck, Uv, Cv, Rk, Rv, bqf);
  prep_wqf<<<dim3(128), dim3(256), 0, stream>>>(w_in, w_q, Wqf);
  prep_gate<<<dim3(DD), dim3(128), 0, stream>>>(w_gate, b_gate, w_out, b_out, Wg1b, Wg2w, Woutb, bgp);

  // Q = visual @ Wqf^T + bqf  (A fp32 -> bf16), optionally side-writing visual_bf16
  if (use_vbf)
    gemm_bt<0, 1, 0, 1><<<dim3(1, NB / 128), dim3(256), 0, stream>>>(
        visual, (long)DD, DD / 32, Wqf, (long)DD,
        bqf, nullptr, nullptr, (short*)vbf, Q, (long)HH);
  else
    gemm_bt<0, 1, 0, 0><<<dim3(1, NB / 128), dim3(256), 0, stream>>>(
        visual, (long)DD, DD / 32, Wqf, (long)DD,
        bqf, nullptr, nullptr, nullptr, Q, (long)HH);

  attn<<<dim3(NB / 8), dim3(128), 0, stream>>>(Q, au, coef, Uk, Ck, Uv, Cv, Rk, Rv, ctx);

  // aon = LN(ctx @ w_ao^T + b_ao)   (A bf16, B fp32) -> bf16 (workspace)
  gemm_bt<1, 0, 1, 0><<<dim3(1, NB / 128), dim3(256), 0, stream>>>(
      ctx, (long)HH, HH / 32, w_ao, (long)HH,
      b_ao, g_aln, b_aln, nullptr, aon, (long)HH);

  // out = sigmoid(visual@Wg1^T + aon@Wg2w^T + bgp) * (aon@Woutb^T + b_out) + (1-g)*visual
  if (use_vbf)
    gemm_final<0><<<dim3(DD / 128, NB / 128), dim3(256), 0, stream>>>(
        vbf, aon, Wg1b, Wg2w, Woutb, bgp, b_out, visual, (float*)d_out);
  else
    gemm_final<1><<<dim3(DD / 128, NB / 128), dim3(256), 0, stream>>>(
        visual, aon, Wg1b, Wg2w, Woutb, bgp, b_out, visual, (float*)d_out);
}

// Round 4
// 498.004 us; speedup vs baseline: 1.1607x; 1.1607x over previous
//
#include <hip/hip_runtime.h>
#include <hip/hip_bf16.h>

typedef __hip_bfloat16 bf16;
typedef __attribute__((ext_vector_type(8))) short short8;
typedef __attribute__((ext_vector_type(4))) float f32x4;
typedef __attribute__((ext_vector_type(8))) __bf16 bf16x8;
typedef const __attribute__((address_space(1))) void* gas_ptr;
typedef __attribute__((address_space(3))) void* las_ptr;

#define NB 32768
#define DD 768
#define AA 17
#define HH 128

__device__ __forceinline__ float bs2f(short s){
  unsigned int u = ((unsigned int)(unsigned short)s) << 16;
  return __builtin_bit_cast(float, u);
}
__device__ __forceinline__ short f2bs(float f){
  bf16 h = __float2bfloat16(f);
  return __builtin_bit_cast(short, h);
}
__device__ __forceinline__ f32x4 mfma16(short8 a, short8 b, f32x4 c){
  return __builtin_amdgcn_mfma_f32_16x16x32_bf16(
      __builtin_bit_cast(bf16x8, a), __builtin_bit_cast(bf16x8, b), c, 0, 0, 0);
}
// async global->LDS, 16B per lane; LDS dest is wave-uniform base + lane*16
__device__ __forceinline__ void glds16(const short* g, short* l){
  __builtin_amdgcn_global_load_lds((gas_ptr)g, (las_ptr)l, 16, 0, 0);
}

// load 8 consecutive elements starting at elem_off; convert to bf16 if F32
template<int F32>
__device__ __forceinline__ short8 ldchunk(const void* base, long elem_off){
  if (F32){
    const float4* p = (const float4*)((const float*)base + elem_off);
    float4 x = p[0], y = p[1];
    short8 r;
    r[0]=f2bs(x.x); r[1]=f2bs(x.y); r[2]=f2bs(x.z); r[3]=f2bs(x.w);
    r[4]=f2bs(y.x); r[5]=f2bs(y.y); r[6]=f2bs(y.z); r[7]=f2bs(y.w);
    return r;
  } else {
    return *(const short8*)((const short*)base + elem_off);
  }
}

// ---------------- prep kernels (all inputs fp32) ----------------

__device__ __forceinline__ float blk_mean128(float v, float* tmp){
  int t = threadIdx.x;
  #pragma unroll
  for (int m = 32; m; m >>= 1) v += __shfl_xor(v, m);
  if ((t & 63) == 0) tmp[t >> 6] = v;
  __syncthreads();
  float r = (tmp[0] + tmp[1]) * (1.0f / 128.0f);
  __syncthreads();
  return r;
}

__global__ void prep1(const float* __restrict__ w_tok, const float* __restrict__ b_tok,
                      const float* __restrict__ pos, const float* __restrict__ g_auln,
                      float* __restrict__ ug, float* __restrict__ rg, float* __restrict__ coef){
  __shared__ float tmp[2];
  int h = threadIdx.x;
  float w = w_tok[h];
  float wbar = blk_mean128(w, tmp);
  float u = w - wbar;
  float g = g_auln[h];
  ug[h] = u * g;
  float muu = blk_mean128(u * u, tmp);
  if (h == 0) coef[0] = muu;
  float bt = b_tok[h];
  for (int a = 0; a < AA; ++a){
    float c = bt + pos[a * HH + h];
    float cbar = blk_mean128(c, tmp);
    float r = c - cbar;
    rg[a * HH + h] = r * g;
    float mur = blk_mean128(u * r, tmp);
    float mrr = blk_mean128(r * r, tmp);
    if (h == 0){ coef[1 + a] = mur; coef[18 + a] = mrr; }
  }
}

__global__ void prep2(const float* __restrict__ w_in, const float* __restrict__ b_in,
                      const float* __restrict__ b_auln, const float* __restrict__ b_q,
                      const float* __restrict__ ug, const float* __restrict__ rg,
                      float* __restrict__ Uk, float* __restrict__ Ck,
                      float* __restrict__ Uv, float* __restrict__ Cv,
                      float* __restrict__ Rk, float* __restrict__ Rv,
                      float* __restrict__ bqf){
  int hp = threadIdx.x, bid = blockIdx.x;
  const float* wqrow = w_in + (long)hp * HH;
  const float* wkrow = w_in + (long)(HH + hp) * HH;
  const float* wvrow = w_in + (long)(2 * HH + hp) * HH;
  if (bid < AA){
    int a = bid;
    float sk = 0.f, sv = 0.f;
    for (int t = 0; t < HH; ++t){
      float r = rg[a * HH + t];
      sk += r * wkrow[t];
      sv += r * wvrow[t];
    }
    Rk[a * HH + hp] = sk; Rv[a * HH + hp] = sv;
  } else if (bid == AA){
    float uk = 0.f, uv = 0.f, ck = 0.f, cv = 0.f;
    for (int t = 0; t < HH; ++t){
      float u = ug[t], ba = b_auln[t];
      float wk = wkrow[t], wv = wvrow[t];
      uk += u * wk; uv += u * wv; ck += ba * wk; cv += ba * wv;
    }
    Uk[hp] = uk; Uv[hp] = uv;
    Ck[hp] = ck + b_in[HH + hp];
    Cv[hp] = cv + b_in[2 * HH + hp];
  } else {
    float s = 0.f;
    for (int t = 0; t < HH; ++t) s += b_q[t] * wqrow[t];
    bqf[hp] = s + b_in[hp];
  }
}

// Wqf[h][j] = sum_t w_in[h][t] * w_q[t][j]  (bf16 out, internal)
__global__ void prep_wqf(const float* __restrict__ w_in, const float* __restrict__ w_q,
                         bf16* __restrict__ Wqf){
  __shared__ float wq[HH];
  int h = blockIdx.x, t = threadIdx.x;
  if (t < HH) wq[t] = w_in[(long)h * HH + t];
  __syncthreads();
  for (int j = t; j < DD; j += 256){
    float acc = 0.f;
    for (int k = 0; k < HH; ++k) acc += wq[k] * w_q[(long)k * DD + j];
    Wqf[(long)h * DD + j] = __float2bfloat16(acc);
  }
}

// Gate-path precompute (one block per output column c of D):
//   Wg1b[c][j]  = bf16(w_gate[c][j])                      j<768   (phase-1 B)
//   Wg2w[c][t]  = bf16( sum_j w_gate[c][768+j]*w_out[j][t] )      (folded phase-2 B)
//   Woutb[c][t] = bf16(w_out[c][t])                               (af B)
//   bgp[c]      = b_gate[c] + sum_j w_gate[c][768+j]*b_out[j]
__global__ void prep_gate(const float* __restrict__ w_gate, const float* __restrict__ b_gate,
                          const float* __restrict__ w_out, const float* __restrict__ b_out,
                          bf16* __restrict__ Wg1b, bf16* __restrict__ Wg2w,
                          bf16* __restrict__ Woutb, float* __restrict__ bgp){
  __shared__ float wg2[DD];
  __shared__ float red[2];
  int c = blockIdx.x, t = threadIdx.x;
  const float* wrow = w_gate + (long)c * (2 * DD);
  for (int j = t; j < DD; j += 128){
    Wg1b[(long)c * DD + j] = __float2bfloat16(wrow[j]);
    wg2[j] = wrow[DD + j];
  }
  __syncthreads();
  float acc = 0.f;
  for (int j = 0; j < DD; ++j) acc = fmaf(wg2[j], w_out[(long)j * HH + t], acc);
  Wg2w[(long)c * HH + t] = __float2bfloat16(acc);
  Woutb[(long)c * HH + t] = __float2bfloat16(w_out[(long)c * HH + t]);
  float pb = 0.f;
  for (int j = t; j < DD; j += 128) pb = fmaf(wg2[j], b_out[j], pb);
  #pragma unroll
  for (int m = 32; m; m >>= 1) pb += __shfl_xor(pb, m);
  if ((t & 63) == 0) red[t >> 6] = pb;
  __syncthreads();
  if (t == 0) bgp[c] = b_gate[c] + red[0] + red[1];
}

// ---------------- attention (folded K/V) ----------------
__global__ __launch_bounds__(128) void attn(
    const bf16* __restrict__ Q, const float* __restrict__ au, const float* __restrict__ coef,
    const float* __restrict__ Uk_, const float* __restrict__ Ck_,
    const float* __restrict__ Uv_, const float* __restrict__ Cv_,
    const float* __restrict__ Rk, const float* __restrict__ Rv,
    bf16* __restrict__ ctx){
  const int ROWS = 8;
  int h = threadIdx.x;
  long row0 = (long)blockIdx.x * ROWS;
  float Uk = Uk_[h], Ck = Ck_[h], Uv = Uv_[h], Cv = Cv_[h];
  float cA = coef[0];
  __shared__ float sa[ROWS * AA];
  for (int idx = h; idx < ROWS * AA; idx += 128)
    sa[idx] = au[row0 * AA + idx];
  __syncthreads();
  const float scale = 0.17677669529663689f; // 1/sqrt(32)
  for (int r = 0; r < ROWS; ++r){
    long row = row0 + r;
    float q = __bfloat162float(Q[row * HH + h]);
    float sc[AA], vv[AA];
    #pragma unroll
    for (int a = 0; a < AA; ++a){
      float s = sa[r * AA + a];
      float var = fmaf(s * s, cA, fmaf(2.f * s, coef[1 + a], coef[18 + a]));
      float rinv = rsqrtf(fmaxf(var, 0.f) + 1e-5f);
      float kk = fmaf(s, Uk, Rk[a * HH + h]) * rinv + Ck;
      vv[a]    = fmaf(s, Uv, Rv[a * HH + h]) * rinv + Cv;
      float p = q * kk;
      p += __shfl_xor(p, 16); p += __shfl_xor(p, 8); p += __shfl_xor(p, 4);
      p += __shfl_xor(p, 2);  p += __shfl_xor(p, 1);
      sc[a] = p * scale;
    }
    float mx = sc[0];
    #pragma unroll
    for (int a = 1; a < AA; ++a) mx = fmaxf(mx, sc[a]);
    float den = 0.f, cval = 0.f;
    #pragma unroll
    for (int a = 0; a < AA; ++a){
      float e = __expf(sc[a] - mx);
      den += e; cval += e * vv[a];
    }
    ctx[row * HH + h] = __float2bfloat16(cval / den);
  }
}

// ---------------- MFMA GEMM (A row-major MxK, B row-major NxK i.e. B^T) ----------------
// Double-buffered LDS, ONE barrier per K-step (reg-staged; used for fp32-source GEMMs).
// MODE 0: out = acc + bias                 -> bf16 (internal)
// MODE 1: out = LayerNorm(acc + bias)*g+b  -> bf16 (internal, full 128-col tile)
// SIDE 1: also write the bf16-converted A tile to sideA (same element pitch as lda)
template<int MODE, int AF, int BF, int SIDE>
__global__ __launch_bounds__(256) void gemm_bt(
    const void* __restrict__ A, long lda, int ks,
    const void* __restrict__ Bw, long ldb,
    const float* __restrict__ bias,
    const float* __restrict__ g_ln, const float* __restrict__ b_ln,
    short* __restrict__ sideA,
    bf16* __restrict__ C, long ldc)
{
  // buf k: As at k*10240, Bs at k*10240+5120 (each 128x40 shorts). epilogue reuses [0,17408)
  __shared__ __align__(16) short smem[20480];
  const int tid = threadIdx.x;
  const int w = tid >> 6, l = tid & 63;
  const long rowBase = (long)blockIdx.y * 128;
  const int colBase = blockIdx.x * 128;
  const int fr = l & 15;          // frag: C/D col within 16 / A row within 16
  const int kq = l >> 4;          // frag k-quad
  const int sr0 = tid >> 2,         sp0 = (tid & 3) * 8;
  const int sr1 = (tid + 256) >> 2;

  f32x4 acc[2][8];
  f32x4 zero = {0.f, 0.f, 0.f, 0.f};
  #pragma unroll
  for (int i = 0; i < 2; ++i)
    #pragma unroll
    for (int j = 0; j < 8; ++j) acc[i][j] = zero;

  // prologue: stage kt=0 into buf0
  {
    short8 av0 = ldchunk<AF>(A, (rowBase + sr0) * lda + sp0);
    short8 av1 = ldchunk<AF>(A, (rowBase + sr1) * lda + sp0);
    short8 bv0 = ldchunk<BF>(Bw, (long)(colBase + sr0) * ldb + sp0);
    short8 bv1 = ldchunk<BF>(Bw, (long)(colBase + sr1) * ldb + sp0);
    if (SIDE){
      *(short8*)(sideA + (rowBase + sr0) * lda + sp0) = av0;
      *(short8*)(sideA + (rowBase + sr1) * lda + sp0) = av1;
    }
    *(short8*)(smem + sr0 * 40 + sp0) = av0;
    *(short8*)(smem + sr1 * 40 + sp0) = av1;
    *(short8*)(smem + 5120 + sr0 * 40 + sp0) = bv0;
    *(short8*)(smem + 5120 + sr1 * 40 + sp0) = bv1;
  }

  for (int kt = 0; kt < ks; ++kt){
    __syncthreads();   // buf[kt&1] staged & prior reads of buf[(kt+1)&1] done
    short* cb = smem + (kt & 1) * 10240;
    short* nb = smem + ((kt + 1) & 1) * 10240;
    const bool pf = (kt + 1 < ks);
    short8 av0, av1, bv0, bv1;
    if (pf){
      const long kA = (long)(kt + 1) * 32;
      av0 = ldchunk<AF>(A, (rowBase + sr0) * lda + kA + sp0);
      av1 = ldchunk<AF>(A, (rowBase + sr1) * lda + kA + sp0);
      bv0 = ldchunk<BF>(Bw, (long)(colBase + sr0) * ldb + kA + sp0);
      bv1 = ldchunk<BF>(Bw, (long)(colBase + sr1) * ldb + kA + sp0);
      if (SIDE){
        *(short8*)(sideA + (rowBase + sr0) * lda + kA + sp0) = av0;
        *(short8*)(sideA + (rowBase + sr1) * lda + kA + sp0) = av1;
      }
    }
    const int ra0 = w * 32 + fr;
    short8 a0 = *(const short8*)(cb + ra0 * 40 + kq * 8);
    short8 a1 = *(const short8*)(cb + (ra0 + 16) * 40 + kq * 8);
    #pragma unroll
    for (int nt = 0; nt < 8; ++nt){
      short8 b = *(const short8*)(cb + 5120 + (nt * 16 + fr) * 40 + kq * 8);
      acc[0][nt] = mfma16(a0, b, acc[0][nt]);
      acc[1][nt] = mfma16(a1, b, acc[1][nt]);
    }
    if (pf){
      *(short8*)(nb + sr0 * 40 + sp0) = av0;
      *(short8*)(nb + sr1 * 40 + sp0) = av1;
      *(short8*)(nb + 5120 + sr0 * 40 + sp0) = bv0;
      *(short8*)(nb + 5120 + sr1 * 40 + sp0) = bv1;
    }
  }
  __syncthreads();  // last frag reads done before epilogue overwrites LDS

  // ---- epilogue: frags -> LDS (bf16) ----
  short* ep = smem;
  if (MODE == 1){
    #pragma unroll
    for (int mt = 0; mt < 2; ++mt){
      #pragma unroll
      for (int r = 0; r < 4; ++r){
        float x[8]; float sm = 0.f, sq = 0.f;
        #pragma unroll
        for (int nt = 0; nt < 8; ++nt){
          const int col = colBase + nt * 16 + fr;
          x[nt] = acc[mt][nt][r] + bias[col];
          sm += x[nt]; sq += x[nt] * x[nt];
        }
        sm += __shfl_xor(sm, 1); sq += __shfl_xor(sq, 1);
        sm += __shfl_xor(sm, 2); sq += __shfl_xor(sq, 2);
        sm += __shfl_xor(sm, 4); sq += __shfl_xor(sq, 4);
        sm += __shfl_xor(sm, 8); sq += __shfl_xor(sq, 8);
        const float mu = sm * (1.f / 128.f);
        const float var = sq * (1.f / 128.f) - mu * mu;
        const float rinv = rsqrtf(fmaxf(var, 0.f) + 1e-5f);
        const int lrow = w * 32 + mt * 16 + kq * 4 + r;
        #pragma unroll
        for (int nt = 0; nt < 8; ++nt){
          const int col = colBase + nt * 16 + fr;
          float y = (x[nt] - mu) * rinv * g_ln[col] + b_ln[col];
          ep[lrow * 136 + nt * 16 + fr] = f2bs(y);
        }
      }
    }
  } else {
    #pragma unroll
    for (int nt = 0; nt < 8; ++nt){
      const int col = colBase + nt * 16 + fr;
      const float bv = bias[col];
      #pragma unroll
      for (int mt = 0; mt < 2; ++mt){
        const int lrow0 = w * 32 + mt * 16 + kq * 4;
        #pragma unroll
        for (int r = 0; r < 4; ++r)
          ep[(lrow0 + r) * 136 + nt * 16 + fr] = f2bs(acc[mt][nt][r] + bv);
      }
    }
  }
  __syncthreads();

  // ---- coalesced bf16 store pass ----
  #pragma unroll
  for (int it = 0; it < 8; ++it){
    const int cid = tid + it * 256;
    const int rw = cid >> 4;
    const int cc = (cid & 15) * 8;
    const long gr = rowBase + rw;
    short8 vls = *(const short8*)(ep + rw * 136 + cc);
    short* cp = (short*)C + gr * ldc + colBase + cc;
    *(short8*)cp = vls;
  }
}

// ---------------- fused gate GEMM ----------------
// accG = A1(visual) @ Wg1b^T  (K=768)  +  aon @ Wg2w^T (K=128)  [gate logits]
// accF = aon @ Woutb^T        (K=128)                           [attn_feat tile]
// out  = sigmoid(accG+bgp) * (accF+b_out) + (1-gate) * visual_fp32
// Phase 1 (A1F=0): global_load_lds dbuf, ONE barrier/K-step, linear LDS [128][32]
//   with source-address swizzle: phys slot s of row r holds logical chunk s^((r>>1)&3).
// Phase 1 (A1F=1, fallback): reg-staged 2-barrier, same swizzled layout.
// Phase 2: 4 steps, classic reg-staged into padded tiles.
template<int A1F>
__global__ __launch_bounds__(256) void gemm_final(
    const void* __restrict__ A1,           // visual: bf16 (A1F=0) or fp32 (A1F=1), pitch DD
    const bf16* __restrict__ aon,          // NB x HH
    const bf16* __restrict__ Wg1b,         // DD x DD
    const bf16* __restrict__ Wg2w,         // DD x HH
    const bf16* __restrict__ Woutb,        // DD x HH
    const float* __restrict__ bgp,         // DD (folded gate bias)
    const float* __restrict__ b_out,       // DD
    const float* __restrict__ vf,          // visual fp32 (epilogue mix)
    float* __restrict__ C)                 // NB x DD fp32
{
  // phase1: buf p at p*8192 shorts (A 4096 + B 4096). phase2: 3 padded tiles at 0/5120/10240.
  __shared__ __align__(16) short smem[16384];
  const int tid = threadIdx.x;
  const int wv = tid >> 6, l = tid & 63;

  // bijective XCD swizzle: nwg = 6*256 = 1536, divisible by 8.
  const int nx = 6;
  const int bid = blockIdx.y * nx + blockIdx.x;   // hw dispatch order (x fastest)
  const int cpx = (NB / 128) * nx / 8;            // 192 blocks per XCD chunk
  const int swz = (bid & 7) * cpx + (bid >> 3);
  const long rowBase = (long)(swz / nx) * 128;
  const int colBase = (swz % nx) * 128;

  const int fr = l & 15;
  const int kq = l >> 4;
  const int swofs = ((kq ^ ((l >> 1) & 3)) << 3);  // read slot (shorts) in linear tiles

  f32x4 accG[2][8], accF[2][8];
  f32x4 zero = {0.f, 0.f, 0.f, 0.f};
  #pragma unroll
  for (int i = 0; i < 2; ++i)
    #pragma unroll
    for (int j = 0; j < 8; ++j){ accG[i][j] = zero; accF[i][j] = zero; }

  // ---- phase 1: visual @ Wg1b^T, K = 768 ----
  if (A1F == 0){
    const short* Ab = (const short*)A1;
    const short* Bb = (const short*)Wg1b;
    const int srow = l >> 2;                                  // 0..15
    const int schunk = ((l & 3) ^ ((l >> 3) & 3)) * 8;        // logical chunk fetched by this lane
    // stage tile kt into buffer p (4 glds per wave: A x2, B x2)
    #define STAGE_P1(p, kt) {                                                        \
      short* dA = smem + (p) * 8192;                                                 \
      _Pragma("unroll")                                                              \
      for (int i = 0; i < 2; ++i){                                                   \
        const int r = wv * 32 + i * 16 + srow;                                       \
        glds16(Ab + ((rowBase + r) * (long)DD + (kt) * 32 + schunk),                 \
               dA + wv * 1024 + i * 512);                                            \
        glds16(Bb + ((long)(colBase + r) * DD + (kt) * 32 + schunk),                 \
               dA + 4096 + wv * 1024 + i * 512);                                     \
      }                                                                              \
    }
    STAGE_P1(0, 0);
    for (int kt = 0; kt < DD / 32; ++kt){
      __syncthreads();                       // drains glds(kt); protects buf^1
      if (kt + 1 < DD / 32) STAGE_P1((kt + 1) & 1, kt + 1);
      short* cb = smem + (kt & 1) * 8192;
      const int ra0 = wv * 32 + fr;
      short8 a0 = *(const short8*)(cb + ra0 * 32 + swofs);
      short8 a1 = *(const short8*)(cb + (ra0 + 16) * 32 + swofs);
      #pragma unroll
      for (int nt = 0; nt < 8; ++nt){
        short8 b = *(const short8*)(cb + 4096 + (nt * 16 + fr) * 32 + swofs);
        accG[0][nt] = mfma16(a0, b, accG[0][nt]);
        accG[1][nt] = mfma16(a1, b, accG[1][nt]);
      }
    }
    #undef STAGE_P1
  } else {
    // fallback: fp32 A, reg-staged, single buffer, 2 barriers, same swizzled layout
    const int sr0 = tid >> 2, sc = tid & 3;
    const int sr1 = sr0 + 64;
    const int sp = sc * 8;
    const int ss0 = (sc ^ ((sr0 >> 1) & 3)) * 8;
    const int ss1 = (sc ^ ((sr1 >> 1) & 3)) * 8;
    for (int kt = 0; kt < DD / 32; ++kt){
      const long kA = (long)kt * 32;
      short8 av0 = ldchunk<1>(A1, (rowBase + sr0) * (long)DD + kA + sp);
      short8 av1 = ldchunk<1>(A1, (rowBase + sr1) * (long)DD + kA + sp);
      short8 bv0 = *(const short8*)((const short*)Wg1b + (long)(colBase + sr0) * DD + kA + sp);
      short8 bv1 = *(const short8*)((const short*)Wg1b + (long)(colBase + sr1) * DD + kA + sp);
      __syncthreads();
      *(short8*)(smem + sr0 * 32 + ss0) = av0;
      *(short8*)(smem + sr1 * 32 + ss1) = av1;
      *(short8*)(smem + 4096 + sr0 * 32 + ss0) = bv0;
      *(short8*)(smem + 4096 + sr1 * 32 + ss1) = bv1;
      __syncthreads();
      const int ra0 = wv * 32 + fr;
      short8 a0 = *(const short8*)(smem + ra0 * 32 + swofs);
      short8 a1 = *(const short8*)(smem + (ra0 + 16) * 32 + swofs);
      #pragma unroll
      for (int nt = 0; nt < 8; ++nt){
        short8 b = *(const short8*)(smem + 4096 + (nt * 16 + fr) * 32 + swofs);
        accG[0][nt] = mfma16(a0, b, accG[0][nt]);
        accG[1][nt] = mfma16(a1, b, accG[1][nt]);
      }
    }
  }

  // ---- phase 2: aon @ {Wg2w, Woutb}^T, K = 128 (padded tiles at 0/5120/10240) ----
  {
    short* As = smem;
    short* Bs = smem + 5120;
    short* Bs2 = smem + 10240;
    const int sr0 = tid >> 2, sp0 = (tid & 3) * 8;
    const int sr1 = sr0 + 64;
    for (int kt = 0; kt < HH / 32; ++kt){
      const long kA = (long)kt * 32;
      short8 av0 = *(const short8*)((const short*)aon + (rowBase + sr0) * HH + kA + sp0);
      short8 av1 = *(const short8*)((const short*)aon + (rowBase + sr1) * HH + kA + sp0);
      short8 bv0 = *(const short8*)((const short*)Wg2w + (long)(colBase + sr0) * HH + kA + sp0);
      short8 bv1 = *(const short8*)((const short*)Wg2w + (long)(colBase + sr1) * HH + kA + sp0);
      short8 cv0 = *(const short8*)((const short*)Woutb + (long)(colBase + sr0) * HH + kA + sp0);
      short8 cv1 = *(const short8*)((const short*)Woutb + (long)(colBase + sr1) * HH + kA + sp0);
      __syncthreads();   // previous reads (phase1 tail / prior kt) complete
      *(short8*)(As + sr0 * 40 + sp0) = av0;
      *(short8*)(As + sr1 * 40 + sp0) = av1;
      *(short8*)(Bs + sr0 * 40 + sp0) = bv0;
      *(short8*)(Bs + sr1 * 40 + sp0) = bv1;
      *(short8*)(Bs2 + sr0 * 40 + sp0) = cv0;
      *(short8*)(Bs2 + sr1 * 40 + sp0) = cv1;
      __syncthreads();
      const int ra0 = wv * 32 + fr;
      short8 a0 = *(const short8*)(As + ra0 * 40 + kq * 8);
      short8 a1 = *(const short8*)(As + (ra0 + 16) * 40 + kq * 8);
      #pragma unroll
      for (int nt = 0; nt < 8; ++nt){
        short8 b  = *(const short8*)(Bs  + (nt * 16 + fr) * 40 + kq * 8);
        short8 b2 = *(const short8*)(Bs2 + (nt * 16 + fr) * 40 + kq * 8);
        accG[0][nt] = mfma16(a0, b,  accG[0][nt]);
        accG[1][nt] = mfma16(a1, b,  accG[1][nt]);
        accF[0][nt] = mfma16(a0, b2, accF[0][nt]);
        accF[1][nt] = mfma16(a1, b2, accF[1][nt]);
      }
    }
  }

  // ---- epilogue: gate-mix directly from registers (fp32 out) ----
  float bg[8], bo[8];
  #pragma unroll
  for (int nt = 0; nt < 8; ++nt){
    const int col = colBase + nt * 16 + fr;
    bg[nt] = bgp[col];
    bo[nt] = b_out[col];
  }
  #pragma unroll
  for (int mt = 0; mt < 2; ++mt){
    const long r0 = rowBase + wv * 32 + mt * 16 + kq * 4;
    #pragma unroll
    for (int r = 0; r < 4; ++r){
      const long row = r0 + r;
      const float* vrow = vf + row * DD;
      float* crow = C + row * DD;
      #pragma unroll
      for (int nt = 0; nt < 8; ++nt){
        const int col = colBase + nt * 16 + fr;
        const float lin = accG[mt][nt][r] + bg[nt];
        const float afv = accF[mt][nt][r] + bo[nt];
        const float gate = 1.f / (1.f + __expf(-lin));
        crow[col] = gate * afv + (1.f - gate) * vrow[col];
      }
    }
  }
}

// ---------------- launch ----------------
// d_out carve (dead before gemm_final writes d_out): Q bf16 [0,8), ctx bf16 [8,16),
// tables [16,~16.3) MB. d_ws: aon + gate tables (~9.6 MB) + optional vbf 48 MB
// (engaged only if ws_size is large enough; all gemm_final INPUTS live outside d_out).
extern "C" void kernel_launch(void* const* d_in, const int* in_sizes, int n_in,
                              void* d_out, int out_size, void* d_ws, size_t ws_size,
                              hipStream_t stream){
  const float* visual = (const float*)d_in[0];
  const float* au     = (const float*)d_in[1];
  const float* w_tok  = (const float*)d_in[2];
  const float* b_tok  = (const float*)d_in[3];
  const float* pos    = (const float*)d_in[4];
  const float* g_auln = (const float*)d_in[5];
  const float* b_auln = (const float*)d_in[6];
  const float* w_q    = (const float*)d_in[7];
  const float* b_q    = (const float*)d_in[8];
  const float* w_in   = (const float*)d_in[9];
  const float* b_in   = (const float*)d_in[10];
  const float* w_ao   = (const float*)d_in[11];
  const float* b_ao   = (const float*)d_in[12];
  const float* g_aln  = (const float*)d_in[13];
  const float* b_aln  = (const float*)d_in[14];
  const float* w_out  = (const float*)d_in[15];
  const float* b_out  = (const float*)d_in[16];
  const float* w_gate = (const float*)d_in[17];
  const float* b_gate = (const float*)d_in[18];

  char* ob = (char*)d_out;
  bf16* Q   = (bf16*)(ob);                       // [0,8MB)
  bf16* ctx = (bf16*)(ob + ((size_t)8 << 20));   // [8,16MB)
  char* p = ob + ((size_t)16 << 20);             // tables (read only by pre-final kernels)
  auto alloc = [&](size_t bytes){ char* r = p; p += (bytes + 255) & ~(size_t)255; return r; };
  bf16*  Wqf  = (bf16*) alloc((size_t)HH * DD * 2);
  float* bqf  = (float*)alloc(HH * 4);
  float* ug   = (float*)alloc(HH * 4);
  float* rg   = (float*)alloc(AA * HH * 4);
  float* coef = (float*)alloc(64 * 4);
  float* Uk   = (float*)alloc(HH * 4);
  float* Ck   = (float*)alloc(HH * 4);
  float* Uv   = (float*)alloc(HH * 4);
  float* Cv   = (float*)alloc(HH * 4);
  float* Rk   = (float*)alloc(AA * HH * 4);
  float* Rv   = (float*)alloc(AA * HH * 4);

  // workspace carve: everything gemm_final READS must live here (it rewrites d_out)
  char* q = (char*)d_ws;
  auto walloc = [&](size_t bytes){ char* r = q; q += (bytes + 255) & ~(size_t)255; return r; };
  bf16*  aon   = (bf16*) walloc((size_t)NB * HH * 2);   // 8 MB
  bf16*  Wg1b  = (bf16*) walloc((size_t)DD * DD * 2);   // 1.125 MB
  bf16*  Wg2w  = (bf16*) walloc((size_t)DD * HH * 2);   // 192 KB
  bf16*  Woutb = (bf16*) walloc((size_t)DD * HH * 2);   // 192 KB
  float* bgp   = (float*)walloc(DD * 4);
  bf16*  vbf   = (bf16*) walloc((size_t)NB * DD * 2);   // 48 MB (optional)
  const bool use_vbf = (size_t)(q - (char*)d_ws) <= ws_size;

  prep1<<<dim3(1), dim3(128), 0, stream>>>(w_tok, b_tok, pos, g_auln, ug, rg, coef);
  prep2<<<dim3(19), dim3(128), 0, stream>>>(w_in, b_in, b_auln, b_q, ug, rg, Uk, Ck, Uv, Cv, Rk, Rv, bqf);
  prep_wqf<<<dim3(128), dim3(256), 0, stream>>>(w_in, w_q, Wqf);
  prep_gate<<<dim3(DD), dim3(128), 0, stream>>>(w_gate, b_gate, w_out, b_out, Wg1b, Wg2w, Woutb, bgp);

  // Q = visual @ Wqf^T + bqf  (A fp32 -> bf16), optionally side-writing visual_bf16
  if (use_vbf)
    gemm_bt<0, 1, 0, 1><<<dim3(1, NB / 128), dim3(256), 0, stream>>>(
        visual, (long)DD, DD / 32, Wqf, (long)DD,
        bqf, nullptr, nullptr, (short*)vbf, Q, (long)HH);
  else
    gemm_bt<0, 1, 0, 0><<<dim3(1, NB / 128), dim3(256), 0, stream>>>(
        visual, (long)DD, DD / 32, Wqf, (long)DD,
        bqf, nullptr, nullptr, nullptr, Q, (long)HH);

  attn<<<dim3(NB / 8), dim3(128), 0, stream>>>(Q, au, coef, Uk, Ck, Uv, Cv, Rk, Rv, ctx);

  // aon = LN(ctx @ w_ao^T + b_ao)   (A bf16, B fp32) -> bf16 (workspace)
  gemm_bt<1, 0, 1, 0><<<dim3(1, NB / 128), dim3(256), 0, stream>>>(
      ctx, (long)HH, HH / 32, w_ao, (long)HH,
      b_ao, g_aln, b_aln, nullptr, aon, (long)HH);

  // out = sigmoid(visual@Wg1^T + aon@Wg2w^T + bgp) * (aon@Woutb^T + b_out) + (1-g)*visual
  if (use_vbf)
    gemm_final<0><<<dim3(DD / 128, NB / 128), dim3(256), 0, stream>>>(
        vbf, aon, Wg1b, Wg2w, Woutb, bgp, b_out, visual, (float*)d_out);
  else
    gemm_final<1><<<dim3(DD / 128, NB / 128), dim3(256), 0, stream>>>(
        visual, aon, Wg1b, Wg2w, Woutb, bgp, b_out, visual, (float*)d_out);
}

// Round 6
// 483.813 us; speedup vs baseline: 1.1948x; 1.0293x over previous
//
#include <hip/hip_runtime.h>
#include <hip/hip_bf16.h>

typedef __hip_bfloat16 bf16;
typedef __attribute__((ext_vector_type(8))) short short8;
typedef __attribute__((ext_vector_type(4))) float f32x4;
typedef __attribute__((ext_vector_type(8))) __bf16 bf16x8;
typedef const __attribute__((address_space(1))) void* gas_ptr;
typedef __attribute__((address_space(3))) void* las_ptr;

#define NB 32768
#define DD 768
#define AA 17
#define HH 128

__device__ __forceinline__ short f2bs(float f){
  bf16 h = __float2bfloat16(f);
  return __builtin_bit_cast(short, h);
}
__device__ __forceinline__ f32x4 mfma16(short8 a, short8 b, f32x4 c){
  return __builtin_amdgcn_mfma_f32_16x16x32_bf16(
      __builtin_bit_cast(bf16x8, a), __builtin_bit_cast(bf16x8, b), c, 0, 0, 0);
}
// async global->LDS, 16B per lane; LDS dest is wave-uniform base + lane*16
__device__ __forceinline__ void glds16(const short* g, short* l){
  __builtin_amdgcn_global_load_lds((gas_ptr)g, (las_ptr)l, 16, 0, 0);
}

// load 8 consecutive elements starting at elem_off; convert to bf16 if F32
template<int F32>
__device__ __forceinline__ short8 ldchunk(const void* base, long elem_off){
  if (F32){
    const float4* p = (const float4*)((const float*)base + elem_off);
    float4 x = p[0], y = p[1];
    short8 r;
    r[0]=f2bs(x.x); r[1]=f2bs(x.y); r[2]=f2bs(x.z); r[3]=f2bs(x.w);
    r[4]=f2bs(y.x); r[5]=f2bs(y.y); r[6]=f2bs(y.z); r[7]=f2bs(y.w);
    return r;
  } else {
    return *(const short8*)((const short*)base + elem_off);
  }
}

// ---------------- prep kernels (all inputs fp32) ----------------

__device__ __forceinline__ float blk_mean128(float v, float* tmp){
  int t = threadIdx.x;
  #pragma unroll
  for (int m = 32; m; m >>= 1) v += __shfl_xor(v, m);
  if ((t & 63) == 0) tmp[t >> 6] = v;
  __syncthreads();
  float r = (tmp[0] + tmp[1]) * (1.0f / 128.0f);
  __syncthreads();
  return r;
}

__global__ void prep1(const float* __restrict__ w_tok, const float* __restrict__ b_tok,
                      const float* __restrict__ pos, const float* __restrict__ g_auln,
                      float* __restrict__ ug, float* __restrict__ rg, float* __restrict__ coef){
  __shared__ float tmp[2];
  int h = threadIdx.x;
  float w = w_tok[h];
  float wbar = blk_mean128(w, tmp);
  float u = w - wbar;
  float g = g_auln[h];
  ug[h] = u * g;
  float muu = blk_mean128(u * u, tmp);
  if (h == 0) coef[0] = muu;
  float bt = b_tok[h];
  for (int a = 0; a < AA; ++a){
    float c = bt + pos[a * HH + h];
    float cbar = blk_mean128(c, tmp);
    float r = c - cbar;
    rg[a * HH + h] = r * g;
    float mur = blk_mean128(u * r, tmp);
    float mrr = blk_mean128(r * r, tmp);
    if (h == 0){ coef[1 + a] = mur; coef[18 + a] = mrr; }
  }
}

__global__ void prep2(const float* __restrict__ w_in, const float* __restrict__ b_in,
                      const float* __restrict__ b_auln, const float* __restrict__ b_q,
                      const float* __restrict__ ug, const float* __restrict__ rg,
                      float* __restrict__ Uk, float* __restrict__ Ck,
                      float* __restrict__ Uv, float* __restrict__ Cv,
                      float* __restrict__ Rk, float* __restrict__ Rv,
                      float* __restrict__ bqf){
  int hp = threadIdx.x, bid = blockIdx.x;
  const float* wqrow = w_in + (long)hp * HH;
  const float* wkrow = w_in + (long)(HH + hp) * HH;
  const float* wvrow = w_in + (long)(2 * HH + hp) * HH;
  if (bid < AA){
    int a = bid;
    float sk = 0.f, sv = 0.f;
    for (int t = 0; t < HH; ++t){
      float r = rg[a * HH + t];
      sk += r * wkrow[t];
      sv += r * wvrow[t];
    }
    Rk[a * HH + hp] = sk; Rv[a * HH + hp] = sv;
  } else if (bid == AA){
    float uk = 0.f, uv = 0.f, ck = 0.f, cv = 0.f;
    for (int t = 0; t < HH; ++t){
      float u = ug[t], ba = b_auln[t];
      float wk = wkrow[t], wv = wvrow[t];
      uk += u * wk; uv += u * wv; ck += ba * wk; cv += ba * wv;
    }
    Uk[hp] = uk; Uv[hp] = uv;
    Ck[hp] = ck + b_in[HH + hp];
    Cv[hp] = cv + b_in[2 * HH + hp];
  } else {
    float s = 0.f;
    for (int t = 0; t < HH; ++t) s += b_q[t] * wqrow[t];
    bqf[hp] = s + b_in[hp];
  }
}

// Wqf[h][j] = sum_t w_in[h][t] * w_q[t][j]  (bf16 out, internal)
__global__ void prep_wqf(const float* __restrict__ w_in, const float* __restrict__ w_q,
                         bf16* __restrict__ Wqf){
  __shared__ float wq[HH];
  int h = blockIdx.x, t = threadIdx.x;
  if (t < HH) wq[t] = w_in[(long)h * HH + t];
  __syncthreads();
  for (int j = t; j < DD; j += 256){
    float acc = 0.f;
    for (int k = 0; k < HH; ++k) acc += wq[k] * w_q[(long)k * DD + j];
    Wqf[(long)h * DD + j] = __float2bfloat16(acc);
  }
}

// Gate-path precompute (one block per output column c of D):
//   Wg1b[c][j]  = bf16(w_gate[c][j])                      j<768   (phase-1 B)
//   Wg2w[c][t]  = bf16( sum_j w_gate[c][768+j]*w_out[j][t] )      (folded phase-2 B)
//   Woutb[c][t] = bf16(w_out[c][t])                               (af B)
//   bgp[c]      = b_gate[c] + sum_j w_gate[c][768+j]*b_out[j]
//   blocks c<HH additionally convert w_ao row c to bf16.
__global__ void prep_gate(const float* __restrict__ w_gate, const float* __restrict__ b_gate,
                          const float* __restrict__ w_out, const float* __restrict__ b_out,
                          const float* __restrict__ w_ao,
                          bf16* __restrict__ Wg1b, bf16* __restrict__ Wg2w,
                          bf16* __restrict__ Woutb, float* __restrict__ bgp,
                          bf16* __restrict__ w_ao_bf){
  __shared__ float wg2[DD];
  __shared__ float red[2];
  int c = blockIdx.x, t = threadIdx.x;
  const float* wrow = w_gate + (long)c * (2 * DD);
  for (int j = t; j < DD; j += 128){
    Wg1b[(long)c * DD + j] = __float2bfloat16(wrow[j]);
    wg2[j] = wrow[DD + j];
  }
  if (c < HH) w_ao_bf[(long)c * HH + t] = __float2bfloat16(w_ao[(long)c * HH + t]);
  __syncthreads();
  float acc = 0.f;
  for (int j = 0; j < DD; ++j) acc = fmaf(wg2[j], w_out[(long)j * HH + t], acc);
  Wg2w[(long)c * HH + t] = __float2bfloat16(acc);
  Woutb[(long)c * HH + t] = __float2bfloat16(w_out[(long)c * HH + t]);
  float pb = 0.f;
  for (int j = t; j < DD; j += 128) pb = fmaf(wg2[j], b_out[j], pb);
  #pragma unroll
  for (int m = 32; m; m >>= 1) pb += __shfl_xor(pb, m);
  if ((t & 63) == 0) red[t >> 6] = pb;
  __syncthreads();
  if (t == 0) bgp[c] = b_gate[c] + red[0] + red[1];
}

// ---------------- attention (folded K/V) ----------------
__global__ __launch_bounds__(128) void attn(
    const bf16* __restrict__ Q, const float* __restrict__ au, const float* __restrict__ coef,
    const float* __restrict__ Uk_, const float* __restrict__ Ck_,
    const float* __restrict__ Uv_, const float* __restrict__ Cv_,
    const float* __restrict__ Rk, const float* __restrict__ Rv,
    bf16* __restrict__ ctx){
  const int ROWS = 8;
  int h = threadIdx.x;
  long row0 = (long)blockIdx.x * ROWS;
  float Uk = Uk_[h], Ck = Ck_[h], Uv = Uv_[h], Cv = Cv_[h];
  float cA = coef[0];
  float rk[AA], rv[AA];
  #pragma unroll
  for (int a = 0; a < AA; ++a){
    rk[a] = Rk[a * HH + h];
    rv[a] = Rv[a * HH + h];
  }
  __shared__ float sa[ROWS * AA];
  for (int idx = h; idx < ROWS * AA; idx += 128)
    sa[idx] = au[row0 * AA + idx];
  __syncthreads();
  const float scale = 0.17677669529663689f; // 1/sqrt(32)
  for (int r = 0; r < ROWS; ++r){
    long row = row0 + r;
    float q = __bfloat162float(Q[row * HH + h]);
    float sc[AA], vv[AA];
    #pragma unroll
    for (int a = 0; a < AA; ++a){
      float s = sa[r * AA + a];
      float var = fmaf(s * s, cA, fmaf(2.f * s, coef[1 + a], coef[18 + a]));
      float rinv = rsqrtf(fmaxf(var, 0.f) + 1e-5f);
      float kk = fmaf(s, Uk, rk[a]) * rinv + Ck;
      vv[a]    = fmaf(s, Uv, rv[a]) * rinv + Cv;
      float p = q * kk;
      p += __shfl_xor(p, 16); p += __shfl_xor(p, 8); p += __shfl_xor(p, 4);
      p += __shfl_xor(p, 2);  p += __shfl_xor(p, 1);
      sc[a] = p * scale;
    }
    float mx = sc[0];
    #pragma unroll
    for (int a = 1; a < AA; ++a) mx = fmaxf(mx, sc[a]);
    float den = 0.f, cval = 0.f;
    #pragma unroll
    for (int a = 0; a < AA; ++a){
      float e = __expf(sc[a] - mx);
      den += e; cval += e * vv[a];
    }
    ctx[row * HH + h] = __float2bfloat16(cval / den);
  }
}

// ---------------- N=128 GEMM: C[M x 128] = A[M x K] @ B[128 x K]^T ----------------
// M-tile 32, 128 threads (2 waves), each wave computes 16 rows x 128 cols.
// B (bf16) staged via glds16 with source swizzle; A reg-staged with 2-deep pipeline
// (load tile kt+2 while writing tile kt+1), swizzled ds_write. One barrier per K-step.
// MODE 0: out = acc + bias -> bf16; MODE 1: LayerNorm(acc+bias)*g+b -> bf16.
// AF: A is fp32 (convert). SIDE: also write bf16 A to sideA (pitch lda).
template<int MODE, int AF, int SIDE>
__global__ __launch_bounds__(128) void gemm_n128(
    const void* __restrict__ A, long lda, int ks,
    const bf16* __restrict__ Bw, long ldb,
    const float* __restrict__ bias,
    const float* __restrict__ g_ln, const float* __restrict__ b_ln,
    short* __restrict__ sideA,
    bf16* __restrict__ C)
{
  // buf p at p*5120 shorts: A [0,1024) (32x32), B [1024,5120) (128x32). 20 KB total.
  __shared__ __align__(16) short smem[10240];
  const int tid = threadIdx.x;
  const int wv = tid >> 6, l = tid & 63;
  const long rowBase = (long)blockIdx.x * 32;
  const int fr = l & 15, kq = l >> 4;
  const int swofs = (kq ^ ((l >> 1) & 3)) << 3;       // read slot (shorts)
  // A staging: thread t stages row t>>2, logical chunk t&3, swizzled phys slot
  const int arow = tid >> 2, ac = tid & 3;
  const int asl = (ac ^ ((arow >> 1) & 3)) * 8;
  // B glds: lane l fetches logical chunk (l&3)^((l>>3)&3) of row base16+(l>>2)
  const int srow = l >> 2;
  const int schunk = ((l & 3) ^ ((l >> 3) & 3)) * 8;

  f32x4 acc[8];
  f32x4 zero = {0.f, 0.f, 0.f, 0.f};
  #pragma unroll
  for (int j = 0; j < 8; ++j) acc[j] = zero;

  short8 avh;   // holds A tile kt+1 at top of iteration kt
  // prologue: stage tile 0 into buf0; preload A tile 1
  {
    short8 av0 = ldchunk<AF>(A, (rowBase + arow) * lda + ac * 8);
    if (SIDE) *(short8*)(sideA + (rowBase + arow) * lda + ac * 8) = av0;
    *(short8*)(smem + arow * 32 + asl) = av0;
    #pragma unroll
    for (int i = 0; i < 4; ++i){
      const int brow = wv * 64 + i * 16 + srow;
      glds16((const short*)Bw + (long)brow * ldb + schunk,
             smem + 1024 + wv * 2048 + i * 512);
    }
    if (ks > 1){
      avh = ldchunk<AF>(A, (rowBase + arow) * lda + 32 + ac * 8);
      if (SIDE) *(short8*)(sideA + (rowBase + arow) * lda + 32 + ac * 8) = avh;
    }
  }
  for (int kt = 0; kt < ks; ++kt){
    __syncthreads();   // buf[kt] staged (glds drained, ds_writes visible)
    short* cb = smem + (kt & 1) * 5120;
    short* nb = smem + ((kt + 1) & 1) * 5120;
    if (kt + 1 < ks){
      *(short8*)(nb + arow * 32 + asl) = avh;            // A tile kt+1
      const long kB = (long)(kt + 1) * 32;
      #pragma unroll
      for (int i = 0; i < 4; ++i){
        const int brow = wv * 64 + i * 16 + srow;
        glds16((const short*)Bw + (long)brow * ldb + kB + schunk,
               nb + 1024 + wv * 2048 + i * 512);
      }
      if (kt + 2 < ks){
        const long kA = (long)(kt + 2) * 32;
        avh = ldchunk<AF>(A, (rowBase + arow) * lda + kA + ac * 8);
        if (SIDE) *(short8*)(sideA + (rowBase + arow) * lda + kA + ac * 8) = avh;
      }
    }
    const int ra = wv * 16 + fr;
    short8 a0 = *(const short8*)(cb + ra * 32 + swofs);
    #pragma unroll
    for (int nt = 0; nt < 8; ++nt){
      short8 b = *(const short8*)(cb + 1024 + (nt * 16 + fr) * 32 + swofs);
      acc[nt] = mfma16(a0, b, acc[nt]);
    }
  }
  __syncthreads();   // frag reads done before epilogue overwrites LDS

  // ---- epilogue: frags -> LDS (bf16), rows wv*16 + kq*4 + r ----
  short* ep = smem;
  if (MODE == 1){
    #pragma unroll
    for (int r = 0; r < 4; ++r){
      float x[8]; float sm = 0.f, sq = 0.f;
      #pragma unroll
      for (int nt = 0; nt < 8; ++nt){
        x[nt] = acc[nt][r] + bias[nt * 16 + fr];
        sm += x[nt]; sq += x[nt] * x[nt];
      }
      sm += __shfl_xor(sm, 1); sq += __shfl_xor(sq, 1);
      sm += __shfl_xor(sm, 2); sq += __shfl_xor(sq, 2);
      sm += __shfl_xor(sm, 4); sq += __shfl_xor(sq, 4);
      sm += __shfl_xor(sm, 8); sq += __shfl_xor(sq, 8);
      const float mu = sm * (1.f / 128.f);
      const float var = sq * (1.f / 128.f) - mu * mu;
      const float rinv = rsqrtf(fmaxf(var, 0.f) + 1e-5f);
      const int lrow = wv * 16 + kq * 4 + r;
      #pragma unroll
      for (int nt = 0; nt < 8; ++nt){
        const int col = nt * 16 + fr;
        float y = (x[nt] - mu) * rinv * g_ln[col] + b_ln[col];
        ep[lrow * 136 + col] = f2bs(y);
      }
    }
  } else {
    #pragma unroll
    for (int nt = 0; nt < 8; ++nt){
      const float bv = bias[nt * 16 + fr];
      #pragma unroll
      for (int r = 0; r < 4; ++r)
        ep[(wv * 16 + kq * 4 + r) * 136 + nt * 16 + fr] = f2bs(acc[nt][r] + bv);
    }
  }
  __syncthreads();

  // ---- coalesced bf16 store (32x128 tile = 512 chunks, 128 threads x 4) ----
  #pragma unroll
  for (int it = 0; it < 4; ++it){
    const int cid = tid + it * 128;
    const int rw = cid >> 4;
    const int cc = (cid & 15) * 8;
    *(short8*)((short*)C + (rowBase + rw) * HH + cc) = *(const short8*)(ep + rw * 136 + cc);
  }
}

// ---------------- fused gate GEMM (128 x 64 tiles) ----------------
// accG = A1(visual) @ Wg1b^T  (K=768)  +  aon @ Wg2w^T (K=128)  [gate logits]
// accF = aon @ Woutb^T        (K=128)                           [attn_feat tile]
// out  = sigmoid(accG+bgp) * (accF+b_out) + (1-gate) * visual_fp32
// Phase 1 (A1F=0): glds dbuf, one barrier/K-step; (A1F=1): reg-staged 2-barrier.
// Phase 2: glds single-buffer, 2 barriers/K-step (all operands internal bf16).
template<int A1F>
__global__ __launch_bounds__(256) void gemm_final(
    const void* __restrict__ A1,           // visual: bf16 (A1F=0) or fp32 (A1F=1), pitch DD
    const bf16* __restrict__ aon,          // NB x HH
    const bf16* __restrict__ Wg1b,         // DD x DD
    const bf16* __restrict__ Wg2w,         // DD x HH
    const bf16* __restrict__ Woutb,        // DD x HH
    const float* __restrict__ bgp,         // DD (folded gate bias)
    const float* __restrict__ b_out,       // DD
    const float* __restrict__ vf,          // visual fp32 (epilogue mix)
    float* __restrict__ C)                 // NB x DD fp32
{
  // phase1 buf p at p*6144 shorts: A [0,4096) 128x32, B [4096,6144) 64x32. 24 KB.
  // phase2 (single buf): A [0,4096), B1 [4096,6144), B2 [6144,8192).
  __shared__ __align__(16) short smem[12288];
  const int tid = threadIdx.x;
  const int wv = tid >> 6, l = tid & 63;

  // bijective XCD swizzle: nwg = 12*256 = 3072, divisible by 8.
  const int nx = 12;
  const int bid = blockIdx.y * nx + blockIdx.x;
  const int cpx = (NB / 128) * nx / 8;            // 384 blocks per XCD chunk
  const int swz = (bid & 7) * cpx + (bid >> 3);
  const long rowBase = (long)(swz / nx) * 128;
  const int colBase = (swz % nx) * 64;

  const int fr = l & 15;
  const int kq = l >> 4;
  const int swofs = (kq ^ ((l >> 1) & 3)) << 3;
  const int srow = l >> 2;
  const int schunk = ((l & 3) ^ ((l >> 3) & 3)) * 8;

  f32x4 accG[2][4], accF[2][4];
  f32x4 zero = {0.f, 0.f, 0.f, 0.f};
  #pragma unroll
  for (int i = 0; i < 2; ++i)
    #pragma unroll
    for (int j = 0; j < 4; ++j){ accG[i][j] = zero; accF[i][j] = zero; }

  // ---- phase 1: visual @ Wg1b^T (cols colBase..+64), K = 768 ----
  if (A1F == 0){
    const short* Ab = (const short*)A1;
    const short* Bb = (const short*)Wg1b;
    #define STAGE_F1(p, kt) {                                                 \
      short* d = smem + (p) * 6144;                                           \
      _Pragma("unroll")                                                       \
      for (int i = 0; i < 2; ++i){                                            \
        const int r = wv * 32 + i * 16 + srow;                                \
        glds16(Ab + (rowBase + r) * (long)DD + (kt) * 32 + schunk,            \
               d + wv * 1024 + i * 512);                                      \
      }                                                                       \
      glds16(Bb + (long)(colBase + wv * 16 + srow) * DD + (kt) * 32 + schunk, \
             d + 4096 + wv * 512);                                            \
    }
    STAGE_F1(0, 0);
    for (int kt = 0; kt < DD / 32; ++kt){
      __syncthreads();
      if (kt + 1 < DD / 32) STAGE_F1((kt + 1) & 1, kt + 1);
      short* cb = smem + (kt & 1) * 6144;
      const int ra0 = wv * 32 + fr;
      short8 a0 = *(const short8*)(cb + ra0 * 32 + swofs);
      short8 a1 = *(const short8*)(cb + (ra0 + 16) * 32 + swofs);
      #pragma unroll
      for (int nt = 0; nt < 4; ++nt){
        short8 b = *(const short8*)(cb + 4096 + (nt * 16 + fr) * 32 + swofs);
        accG[0][nt] = mfma16(a0, b, accG[0][nt]);
        accG[1][nt] = mfma16(a1, b, accG[1][nt]);
      }
    }
    #undef STAGE_F1
  } else {
    // fallback: fp32 A reg-staged, single buffer [0,6144), 2 barriers per K-step
    const int r0 = tid >> 2, ac = tid & 3;
    const int s0 = (ac ^ ((r0 >> 1) & 3)) * 8;   // same for r0 and r0+64
    for (int kt = 0; kt < DD / 32; ++kt){
      const long kA = (long)kt * 32;
      short8 av0 = ldchunk<1>(A1, (rowBase + r0) * (long)DD + kA + ac * 8);
      short8 av1 = ldchunk<1>(A1, (rowBase + 64 + r0) * (long)DD + kA + ac * 8);
      short8 bv  = *(const short8*)((const short*)Wg1b + (long)(colBase + r0) * DD + kA + ac * 8);
      __syncthreads();
      *(short8*)(smem + r0 * 32 + s0) = av0;
      *(short8*)(smem + (64 + r0) * 32 + s0) = av1;
      *(short8*)(smem + 4096 + r0 * 32 + s0) = bv;
      __syncthreads();
      const int ra0 = wv * 32 + fr;
      short8 a0 = *(const short8*)(smem + ra0 * 32 + swofs);
      short8 a1 = *(const short8*)(smem + (ra0 + 16) * 32 + swofs);
      #pragma unroll
      for (int nt = 0; nt < 4; ++nt){
        short8 b = *(const short8*)(smem + 4096 + (nt * 16 + fr) * 32 + swofs);
        accG[0][nt] = mfma16(a0, b, accG[0][nt]);
        accG[1][nt] = mfma16(a1, b, accG[1][nt]);
      }
    }
  }

  // ---- phase 2: aon @ {Wg2w, Woutb}^T, K = 128, glds single-buffer ----
  for (int kt = 0; kt < HH / 32; ++kt){
    __syncthreads();             // prior reads (phase1 tail / prior kt) done
    const long kA = (long)kt * 32;
    #pragma unroll
    for (int i = 0; i < 2; ++i){
      const int r = wv * 32 + i * 16 + srow;
      glds16((const short*)aon + (rowBase + r) * HH + kA + schunk,
             smem + wv * 1024 + i * 512);
    }
    glds16((const short*)Wg2w + (long)(colBase + wv * 16 + srow) * HH + kA + schunk,
           smem + 4096 + wv * 512);
    glds16((const short*)Woutb + (long)(colBase + wv * 16 + srow) * HH + kA + schunk,
           smem + 6144 + wv * 512);
    __syncthreads();             // glds drained
    const int ra0 = wv * 32 + fr;
    short8 a0 = *(const short8*)(smem + ra0 * 32 + swofs);
    short8 a1 = *(const short8*)(smem + (ra0 + 16) * 32 + swofs);
    #pragma unroll
    for (int nt = 0; nt < 4; ++nt){
      short8 b  = *(const short8*)(smem + 4096 + (nt * 16 + fr) * 32 + swofs);
      short8 b2 = *(const short8*)(smem + 6144 + (nt * 16 + fr) * 32 + swofs);
      accG[0][nt] = mfma16(a0, b,  accG[0][nt]);
      accG[1][nt] = mfma16(a1, b,  accG[1][nt]);
      accF[0][nt] = mfma16(a0, b2, accF[0][nt]);
      accF[1][nt] = mfma16(a1, b2, accF[1][nt]);
    }
  }

  // ---- epilogue: gate-mix directly from registers (fp32 out) ----
  float bg[4], bo[4];
  #pragma unroll
  for (int nt = 0; nt < 4; ++nt){
    const int col = colBase + nt * 16 + fr;
    bg[nt] = bgp[col];
    bo[nt] = b_out[col];
  }
  #pragma unroll
  for (int mt = 0; mt < 2; ++mt){
    const long r0 = rowBase + wv * 32 + mt * 16 + kq * 4;
    #pragma unroll
    for (int r = 0; r < 4; ++r){
      const long row = r0 + r;
      const float* vrow = vf + row * DD;
      float* crow = C + row * DD;
      #pragma unroll
      for (int nt = 0; nt < 4; ++nt){
        const int col = colBase + nt * 16 + fr;
        const float lin = accG[mt][nt][r] + bg[nt];
        const float afv = accF[mt][nt][r] + bo[nt];
        const float gate = 1.f / (1.f + __expf(-lin));
        crow[col] = gate * afv + (1.f - gate) * vrow[col];
      }
    }
  }
}

// ---------------- launch ----------------
// d_out carve (dead before gemm_final writes d_out): Q bf16 [0,8), ctx bf16 [8,16),
// tables [16,~16.5) MB. d_ws: aon + gate tables (~9.6 MB) + optional vbf 48 MB
// (engaged only if ws_size is large enough; all gemm_final INPUTS live outside d_out).
extern "C" void kernel_launch(void* const* d_in, const int* in_sizes, int n_in,
                              void* d_out, int out_size, void* d_ws, size_t ws_size,
                              hipStream_t stream){
  const float* visual = (const float*)d_in[0];
  const float* au     = (const float*)d_in[1];
  const float* w_tok  = (const float*)d_in[2];
  const float* b_tok  = (const float*)d_in[3];
  const float* pos    = (const float*)d_in[4];
  const float* g_auln = (const float*)d_in[5];
  const float* b_auln = (const float*)d_in[6];
  const float* w_q    = (const float*)d_in[7];
  const float* b_q    = (const float*)d_in[8];
  const float* w_in   = (const float*)d_in[9];
  const float* b_in   = (const float*)d_in[10];
  const float* w_ao   = (const float*)d_in[11];
  const float* b_ao   = (const float*)d_in[12];
  const float* g_aln  = (const float*)d_in[13];
  const float* b_aln  = (const float*)d_in[14];
  const float* w_out  = (const float*)d_in[15];
  const float* b_out  = (const float*)d_in[16];
  const float* w_gate = (const float*)d_in[17];
  const float* b_gate = (const float*)d_in[18];

  char* ob = (char*)d_out;
  bf16* Q   = (bf16*)(ob);                       // [0,8MB)
  bf16* ctx = (bf16*)(ob + ((size_t)8 << 20));   // [8,16MB)
  char* p = ob + ((size_t)16 << 20);             // tables (read only by pre-final kernels)
  auto alloc = [&](size_t bytes){ char* r = p; p += (bytes + 255) & ~(size_t)255; return r; };
  bf16*  Wqf     = (bf16*) alloc((size_t)HH * DD * 2);
  bf16*  w_ao_bf = (bf16*) alloc((size_t)HH * HH * 2);
  float* bqf  = (float*)alloc(HH * 4);
  float* ug   = (float*)alloc(HH * 4);
  float* rg   = (float*)alloc(AA * HH * 4);
  float* coef = (float*)alloc(64 * 4);
  float* Uk   = (float*)alloc(HH * 4);
  float* Ck   = (float*)alloc(HH * 4);
  float* Uv   = (float*)alloc(HH * 4);
  float* Cv   = (float*)alloc(HH * 4);
  float* Rk   = (float*)alloc(AA * HH * 4);
  float* Rv   = (float*)alloc(AA * HH * 4);

  // workspace carve: everything gemm_final READS must live here (it rewrites d_out)
  char* q = (char*)d_ws;
  auto walloc = [&](size_t bytes){ char* r = q; q += (bytes + 255) & ~(size_t)255; return r; };
  bf16*  aon   = (bf16*) walloc((size_t)NB * HH * 2);   // 8 MB
  bf16*  Wg1b  = (bf16*) walloc((size_t)DD * DD * 2);   // 1.125 MB
  bf16*  Wg2w  = (bf16*) walloc((size_t)DD * HH * 2);   // 192 KB
  bf16*  Woutb = (bf16*) walloc((size_t)DD * HH * 2);   // 192 KB
  float* bgp   = (float*)walloc(DD * 4);
  bf16*  vbf   = (bf16*) walloc((size_t)NB * DD * 2);   // 48 MB (optional)
  const bool use_vbf = (size_t)(q - (char*)d_ws) <= ws_size;

  prep1<<<dim3(1), dim3(128), 0, stream>>>(w_tok, b_tok, pos, g_auln, ug, rg, coef);
  prep2<<<dim3(19), dim3(128), 0, stream>>>(w_in, b_in, b_auln, b_q, ug, rg, Uk, Ck, Uv, Cv, Rk, Rv, bqf);
  prep_wqf<<<dim3(128), dim3(256), 0, stream>>>(w_in, w_q, Wqf);
  prep_gate<<<dim3(DD), dim3(128), 0, stream>>>(w_gate, b_gate, w_out, b_out, w_ao,
                                                Wg1b, Wg2w, Woutb, bgp, w_ao_bf);

  // Q = visual @ Wqf^T + bqf  (A fp32 -> bf16), optionally side-writing visual_bf16
  if (use_vbf)
    gemm_n128<0, 1, 1><<<dim3(NB / 32), dim3(128), 0, stream>>>(
        visual, (long)DD, DD / 32, Wqf, (long)DD,
        bqf, nullptr, nullptr, (short*)vbf, Q);
  else
    gemm_n128<0, 1, 0><<<dim3(NB / 32), dim3(128), 0, stream>>>(
        visual, (long)DD, DD / 32, Wqf, (long)DD,
        bqf, nullptr, nullptr, nullptr, Q);

  attn<<<dim3(NB / 8), dim3(128), 0, stream>>>(Q, au, coef, Uk, Ck, Uv, Cv, Rk, Rv, ctx);

  // aon = LN(ctx @ w_ao^T + b_ao)   (A bf16, B bf16) -> bf16 (workspace)
  gemm_n128<1, 0, 0><<<dim3(NB / 32), dim3(128), 0, stream>>>(
      ctx, (long)HH, HH / 32, w_ao_bf, (long)HH,
      b_ao, g_aln, b_aln, nullptr, aon);

  // out = sigmoid(visual@Wg1^T + aon@Wg2w^T + bgp) * (aon@Woutb^T + b_out) + (1-g)*visual
  if (use_vbf)
    gemm_final<0><<<dim3(12, NB / 128), dim3(256), 0, stream>>>(
        vbf, aon, Wg1b, Wg2w, Woutb, bgp, b_out, visual, (float*)d_out);
  else
    gemm_final<1><<<dim3(12, NB / 128), dim3(256), 0, stream>>>(
        visual, aon, Wg1b, Wg2w, Woutb, bgp, b_out, visual, (float*)d_out);
}